// Round 1
// baseline (427.872 us; speedup 1.0000x reference)
//
#include <hip/hip_runtime.h>
#include <stdint.h>

typedef int v4i  __attribute__((ext_vector_type(4)));
typedef int v16i __attribute__((ext_vector_type(16)));

static constexpr int Mdim = 4096;   // B*S
static constexpr int Ndim = 4096;   // D_OUT
static constexpr int Kdim = 4096;   // D_IN

// tiled plane layout: idx(row,k) = (row>>7)*524288 + (k>>4)*2048 + (row&127)*16 + (k&15)
static constexpr size_t TILE_BYTES  = 128u * 4096u;          // 524288
static constexpr size_t OFF_ROWPAR  = 4096;                  // 4096 rows * 16B
static constexpr size_t OFF_BT      = 1u << 20;              // 16 MiB ternary weights
static constexpr size_t OFF_A0      = 17u << 20;             // 3 x 16 MiB limb planes
static constexpr size_t PLANE_BYTES = 16u << 20;

__device__ __forceinline__ void gload16(const void* g, void* l) {
  __builtin_amdgcn_global_load_lds(
      (const __attribute__((address_space(1))) char*)g,
      (__attribute__((address_space(3))) char*)l, 16, 0, 0);
}

// ---------------- K1: sum |round(w*2^16)| ----------------
__global__ void k_wsum(const float* __restrict__ w, unsigned long long* __restrict__ ws) {
  int tid = blockIdx.x * blockDim.x + threadIdx.x;
  int stride = gridDim.x * blockDim.x;
  const float4* w4 = (const float4*)w;
  const int n4 = (Ndim * Kdim) / 4;
  unsigned long long s = 0;
  for (int i = tid; i < n4; i += stride) {
    float4 v = w4[i];
    long long a = llrintf(v.x * 65536.f);
    long long b = llrintf(v.y * 65536.f);
    long long c = llrintf(v.z * 65536.f);
    long long d = llrintf(v.w * 65536.f);
    s += (unsigned long long)(a < 0 ? -a : a) + (unsigned long long)(b < 0 ? -b : b)
       + (unsigned long long)(c < 0 ? -c : c) + (unsigned long long)(d < 0 ? -d : d);
  }
  #pragma unroll
  for (int off = 32; off > 0; off >>= 1) s += __shfl_down(s, off, 64);
  if ((threadIdx.x & 63) == 0) atomicAdd(ws, s);
}

// ---------------- K1b: scalars ----------------
__global__ void k_scalars(unsigned long long* ws) {
  unsigned long long s = ws[0];
  long long mean_abs = (long long)(s >> 24);            // / (4096*4096)
  if (mean_abs < 1) mean_abs = 1;
  long long siw = (long long)((1ULL << 32) / (unsigned long long)mean_abs);
  ((long long*)ws)[1] = siw;
  ((long long*)ws)[2] = mean_abs;
}

// ---------------- K2: ternarize weights into tiled layout ----------------
__global__ void k_tern(const float* __restrict__ w, const long long* __restrict__ scal,
                       int8_t* __restrict__ bt) {
  int t = blockIdx.x * 256 + threadIdx.x;   // 1,048,576 threads, one 16B chunk each
  long long mean_abs = scal[2];
  int nt = t >> 15;            // 32768 chunks per 128-row tile
  int kc = (t >> 7) & 255;
  int r  = t & 127;
  int row = nt * 128 + r;
  const float4* src = (const float4*)(w + (size_t)row * Kdim + kc * 16);
  int words[4];
  #pragma unroll
  for (int j = 0; j < 4; ++j) {
    float4 v = src[j];
    float e0 = v.x, e1 = v.y, e2 = v.z, e3 = v.w;
    int wrd = 0;
    long long f;
    f = llrintf(e0 * 65536.f); wrd |= ((f < 0 ? -1 : (f >= mean_abs ? 1 : 0)) & 0xff);
    f = llrintf(e1 * 65536.f); wrd |= ((f < 0 ? -1 : (f >= mean_abs ? 1 : 0)) & 0xff) << 8;
    f = llrintf(e2 * 65536.f); wrd |= ((f < 0 ? -1 : (f >= mean_abs ? 1 : 0)) & 0xff) << 16;
    f = llrintf(e3 * 65536.f); wrd |= ((f < 0 ? -1 : (f >= mean_abs ? 1 : 0)) & 0xff) << 24;
    words[j] = wrd;
  }
  *(int4*)(bt + (size_t)nt * TILE_BYTES + (size_t)kc * 2048 + (size_t)r * 16) =
      make_int4(words[0], words[1], words[2], words[3]);
}

// ---------------- K3a: per-row max -> scale, scale_inv ----------------
__global__ void k_rowmax(const float* __restrict__ x, long long* __restrict__ rowpar) {
  int m = blockIdx.x;
  const float4* xr = (const float4*)(x + (size_t)m * Kdim);
  long long mx = 0;
  #pragma unroll
  for (int j = 0; j < 4; ++j) {
    float4 v = xr[j * 256 + threadIdx.x];
    long long a = llrintf(v.x * 65536.f); a = a < 0 ? -a : a; mx = a > mx ? a : mx;
    long long b = llrintf(v.y * 65536.f); b = b < 0 ? -b : b; mx = b > mx ? b : mx;
    long long c = llrintf(v.z * 65536.f); c = c < 0 ? -c : c; mx = c > mx ? c : mx;
    long long d = llrintf(v.w * 65536.f); d = d < 0 ? -d : d; mx = d > mx ? d : mx;
  }
  #pragma unroll
  for (int off = 32; off > 0; off >>= 1) {
    long long o = __shfl_down(mx, off, 64);
    mx = o > mx ? o : mx;
  }
  __shared__ long long red[4];
  if ((threadIdx.x & 63) == 0) red[threadIdx.x >> 6] = mx;
  __syncthreads();
  if (threadIdx.x == 0) {
    long long m0 = red[0];
    m0 = red[1] > m0 ? red[1] : m0;
    m0 = red[2] > m0 ? red[2] : m0;
    m0 = red[3] > m0 ? red[3] : m0;
    if (m0 < 1) m0 = 1;   // guard (min_val==0 in reference; all-zero row impossible)
    long long scale = (long long)((127ULL << 32) / (unsigned long long)m0);
    long long sinv  = (long long)((1ULL << 32) / (unsigned long long)scale);
    rowpar[2 * m]     = scale;
    rowpar[2 * m + 1] = sinv;
  }
}

// ---------------- K3b: activation quant -> 3 int8 limb planes (tiled) ----------------
__global__ void k_actq(const float* __restrict__ x, const long long* __restrict__ rowpar,
                       int8_t* __restrict__ a0, int8_t* __restrict__ a1, int8_t* __restrict__ a2) {
  int t = blockIdx.x * 256 + threadIdx.x;
  int mt = t >> 15;
  int kc = (t >> 7) & 255;
  int r  = t & 127;
  int m = mt * 128 + r;
  long long scale = rowpar[2 * m];
  long long sinv  = rowpar[2 * m + 1];
  const float4* src = (const float4*)(x + (size_t)m * Kdim + kc * 16);
  int w0[4], w1[4], w2[4];
  #pragma unroll
  for (int j = 0; j < 4; ++j) {
    float4 v = src[j];
    float e[4] = {v.x, v.y, v.z, v.w};
    int r0 = 0, r1 = 0, r2 = 0;
    #pragma unroll
    for (int q = 0; q < 4; ++q) {
      long long xf = llrintf(e[q] * 65536.f);
      long long xs = (xf * scale) >> 16;
      if (xs < -8388608LL) xs = -8388608LL;
      else if (xs > 8323072LL) xs = 8323072LL;
      int xq = (int)((xs * sinv) >> 16);
      int l0 = ((xq + 128) & 255) - 128;
      int tt = (xq - l0) >> 8;
      int l1 = ((tt + 128) & 255) - 128;
      int l2 = (tt - l1) >> 8;
      r0 |= (l0 & 0xff) << (8 * q);
      r1 |= (l1 & 0xff) << (8 * q);
      r2 |= (l2 & 0xff) << (8 * q);
    }
    w0[j] = r0; w1[j] = r1; w2[j] = r2;
  }
  size_t idx = (size_t)mt * TILE_BYTES + (size_t)kc * 2048 + (size_t)r * 16;
  *(int4*)(a0 + idx) = make_int4(w0[0], w0[1], w0[2], w0[3]);
  *(int4*)(a1 + idx) = make_int4(w1[0], w1[1], w1[2], w1[3]);
  *(int4*)(a2 + idx) = make_int4(w2[0], w2[1], w2[2], w2[3]);
}

// ---------------- K4: 3-limb i8 MFMA GEMM ----------------
__launch_bounds__(512, 2)
__global__ void k_gemm(const int8_t* __restrict__ a0, const int8_t* __restrict__ a1,
                       const int8_t* __restrict__ a2, const int8_t* __restrict__ bt,
                       const long long* __restrict__ scal, float* __restrict__ out) {
  __shared__ __attribute__((aligned(16))) char lds[2][4][8192]; // [buf][A0,A1,A2,B]
  int bx = blockIdx.x;
  int mt = bx >> 5;
  int nt = bx & 31;
  int tid  = threadIdx.x;
  int lane = tid & 63;
  int w    = tid >> 6;
  int wm   = w >> 1;   // 0..3 -> 32-row slice
  int wn   = w & 1;    // 0..1 -> 64-col slice

  const char* planes[4];
  planes[0] = (const char*)a0 + (size_t)mt * TILE_BYTES;
  planes[1] = (const char*)a1 + (size_t)mt * TILE_BYTES;
  planes[2] = (const char*)a2 + (size_t)mt * TILE_BYTES;
  planes[3] = (const char*)bt + (size_t)nt * TILE_BYTES;

  v16i acc[2][3] = {};

  auto STAGE = [&](int buf, int kt) {
    #pragma unroll
    for (int p = 0; p < 4; ++p)
      gload16(planes[p] + (size_t)kt * 8192 + (size_t)tid * 16, &lds[buf][p][tid * 16]);
  };

  auto COMPUTE = [&](int buf) {
    #pragma unroll
    for (int ks = 0; ks < 2; ++ks) {
      const int koff = (ks * 2 + (lane >> 5)) * 2048;
      v4i bfrag[2], afrag[3];
      #pragma unroll
      for (int nj = 0; nj < 2; ++nj)
        bfrag[nj] = *(const v4i*)&lds[buf][3][koff + (wn * 64 + nj * 32 + (lane & 31)) * 16];
      #pragma unroll
      for (int p = 0; p < 3; ++p)
        afrag[p] = *(const v4i*)&lds[buf][p][koff + (wm * 32 + (lane & 31)) * 16];
      #pragma unroll
      for (int nj = 0; nj < 2; ++nj)
        #pragma unroll
        for (int p = 0; p < 3; ++p)
          acc[nj][p] = __builtin_amdgcn_mfma_i32_32x32x32_i8(afrag[p], bfrag[nj], acc[nj][p], 0, 0, 0);
    }
  };

  STAGE(0, 0);
  __syncthreads();
  const int NT = Kdim / 64;   // 64 K-tiles
  for (int kt = 0; kt < NT; ++kt) {
    int cur = kt & 1;
    if (kt + 1 < NT) STAGE(cur ^ 1, kt + 1);  // issue next-tile loads (overlap with compute)
    COMPUTE(cur);
    __syncthreads();                           // drains vmcnt(0) -> next buffer ready
  }

  // epilogue
  long long siw = scal[1];
  int m0 = mt * 128 + wm * 32;
  int n0 = nt * 128 + wn * 64;
  #pragma unroll
  for (int nj = 0; nj < 2; ++nj) {
    #pragma unroll
    for (int rg = 0; rg < 16; ++rg) {
      unsigned u = (unsigned)acc[nj][0][rg]
                 + ((unsigned)acc[nj][1][rg] << 8)
                 + ((unsigned)acc[nj][2][rg] << 16);
      long long v = ((long long)(int)u * siw) >> 16;
      int row = (rg & 3) + 8 * (rg >> 2) + 4 * (lane >> 5);
      int col = nj * 32 + (lane & 31);
      out[(size_t)(m0 + row) * Ndim + (n0 + col)] = (float)v * (1.f / 65536.f);
    }
  }
}

extern "C" void kernel_launch(void* const* d_in, const int* in_sizes, int n_in,
                              void* d_out, int out_size, void* d_ws, size_t ws_size,
                              hipStream_t stream) {
  const float* x = (const float*)d_in[0];
  const float* w = (const float*)d_in[1];
  float* out = (float*)d_out;
  char* ws = (char*)d_ws;

  unsigned long long* scal = (unsigned long long*)ws;
  long long* rowpar = (long long*)(ws + OFF_ROWPAR);
  int8_t* bt = (int8_t*)(ws + OFF_BT);
  int8_t* a0 = (int8_t*)(ws + OFF_A0);
  int8_t* a1 = a0 + PLANE_BYTES;
  int8_t* a2 = a1 + PLANE_BYTES;

  hipMemsetAsync(ws, 0, 64, stream);
  k_wsum<<<1024, 256, 0, stream>>>(w, scal);
  k_scalars<<<1, 1, 0, stream>>>(scal);
  k_tern<<<4096, 256, 0, stream>>>(w, (const long long*)scal, bt);
  k_rowmax<<<4096, 256, 0, stream>>>(x, rowpar);
  k_actq<<<4096, 256, 0, stream>>>(x, rowpar, a0, a1, a2);
  k_gemm<<<1024, 512, 0, stream>>>(a0, a1, a2, bt, (const long long*)scal, out);
}